// Round 1
// 220.914 us; speedup vs baseline: 1.1500x; 1.1500x over previous
//
#include <hip/hip_runtime.h>

// BertSelfAttention on MI355X: bf16 MFMA QKV GEMM + flash-style attention.
// B=8 S=1024 HID=1024 NH=16 HD=64.
// R7: k_gemm rewritten as the 256x256 8-phase schedule (plain-HIP port of the
// verified learn_hip m201 template): BK=64, 8 waves (512 thr), 2x64KB LDS
// double-buffer, st_16x32 XOR swizzle (pre-swizzled global source + swizzled
// ds_read_b128 -> conflict-free), counted s_waitcnt vmcnt(4) only at phases
// 4/8 (never 0 mid-loop), setprio(1) around MFMA clusters, sched_barrier(0)
// fences (rule #18), bijective XCD block swizzle. Epilogue re-derived for the
// 16x16x32 C layout (col=lane&15, row=(lane>>4)*4+e); V^T stored directly as
// uint2 runs (4 consecutive s per lane), no LDS bounce.
// k_prep / k_attn unchanged from R6.

typedef __bf16 bf16x8 __attribute__((ext_vector_type(8)));
typedef float f32x4 __attribute__((ext_vector_type(4)));
typedef float f32x16 __attribute__((ext_vector_type(16)));
typedef int i32x4 __attribute__((ext_vector_type(4)));

__device__ __forceinline__ unsigned rne16(float x) {
  unsigned u = __builtin_bit_cast(unsigned, x);
  return (u + 0x7fffu + ((u >> 16) & 1u)) >> 16;
}
__device__ __forceinline__ unsigned packbf(float lo, float hi) {
  return rne16(lo) | (rne16(hi) << 16);
}
// fast pack (round-half-up) for softmax probabilities.
__device__ __forceinline__ unsigned packbf_fast(float lo, float hi) {
  unsigned ul = __builtin_bit_cast(unsigned, lo) + 0x8000u;
  unsigned uh = __builtin_bit_cast(unsigned, hi) + 0x8000u;
  return __builtin_amdgcn_perm(uh, ul, 0x07060302u);
}
// async global->LDS, 16B per lane; LDS dst is wave-uniform base + lane*16.
__device__ __forceinline__ void async16(void* l, const void* g) {
  __builtin_amdgcn_global_load_lds((const __attribute__((address_space(1))) void*)g,
                                   (__attribute__((address_space(3))) void*)l, 16, 0, 0);
}
// inline-asm ds_read_b128 (compiler must not see an LDS dependence; ordering is
// enforced by barriers + explicit waitcnt + sched_barrier(0) per rule #18).
__device__ __forceinline__ bf16x8 dsr128(const char* p) {
  i32x4 r;
  unsigned a = (unsigned)(size_t)(const __attribute__((address_space(3))) char*)p;
  asm volatile("ds_read_b128 %0, %1" : "=v"(r) : "v"(a));
  return __builtin_bit_cast(bf16x8, r);
}

// ---------------- fused: hidden fp32->bf16 (blocks 0..8191) + W transpose (8192..11263) ----
__global__ __launch_bounds__(256) void k_prep(const float* __restrict__ h,
                                              unsigned short* __restrict__ hbf,
                                              const float* __restrict__ Wq,
                                              const float* __restrict__ Wk,
                                              const float* __restrict__ Wv,
                                              unsigned short* __restrict__ wt) {
  __shared__ float t[32][33];
  int bid = blockIdx.x, tid = threadIdx.x;
  if (bid < 8192) {
    size_t i = (size_t)bid * 256 + tid;
    float4 v = ((const float4*)h)[i];
    uint2 r;
    r.x = packbf(v.x, v.y);
    r.y = packbf(v.z, v.w);
    ((uint2*)hbf)[i] = r;
  } else {
    int id = bid - 8192;           // 0..3071
    int which = id >> 10;
    int sub = id & 1023;
    int c0 = (sub & 31) * 32, k0 = (sub >> 5) * 32;
    const float* W = which == 0 ? Wq : (which == 1 ? Wk : Wv);
    int tx = tid & 31, ty = tid >> 5;
#pragma unroll
    for (int i = 0; i < 4; ++i) {
      int r = ty + i * 8;
      t[r][tx] = W[(size_t)(k0 + r) * 1024 + c0 + tx];
    }
    __syncthreads();
#pragma unroll
    for (int i = 0; i < 4; ++i) {
      int r = ty + i * 8;
      wt[((size_t)which * 1024 + c0 + r) * 1024 + k0 + tx] = (unsigned short)rne16(t[tx][r]);
    }
  }
}

// ---------------- QKV GEMM: [8192x1024] x [1024x3072]^T + bias, 8-phase 256x256 ----------------
// LDS per double-buffer d (64KB each): A [256][64] at d*65536 (halves +0/+16384),
// B [256][64] at d*65536+32768 (halves +32768/+49152). Within each 1KB subtile
// (16 rows x 32 cols bf16) the byte offset is XOR-swizzled: off ^= ((off>>9)&1)<<5.
// Issue schedule per iteration (tiles u=2i in db0 phases 1-4, v=2i+1 in db1 5-8):
//  P1: v.A0+A1 -> db1.A (freed by prev P8)   P5: (u+2).A0+A1 -> db0.A (freed P4)
//  P2: (u+2).B0 -> db0.B (freed P1)          P6: (v+2).B0 -> db1.B (freed P5)
//  P3: (u+2).B1                              P7: (v+2).B1
//  P4: vmcnt(4) [v fully landed]             P8: vmcnt(4) [u+2 fully landed]
// Steady state: 2 half-tiles (4 loads/lane) in flight across each wait.
__global__ __launch_bounds__(512, 2) void k_gemm(const unsigned short* __restrict__ A,
                                                 const unsigned short* __restrict__ Bm,
                                                 const float* __restrict__ bq,
                                                 const float* __restrict__ bk,
                                                 const float* __restrict__ bv,
                                                 unsigned short* __restrict__ qkv,
                                                 unsigned short* __restrict__ vt) {
  __shared__ __align__(16) char lds[131072];
  const int tid = threadIdx.x;
  const int w = tid >> 6, lane = tid & 63;
  const int wm = w >> 2, wn = w & 3;

  // bijective XCD swizzle: 384 blocks = 8 XCDs x 48; tn fastest within a chunk
  // so each XCD's L2 holds 4 A-panels (2MB) + the rotating B panel.
  int orig = blockIdx.x;
  int wgid = (orig & 7) * 48 + (orig >> 3);
  int tm = wgid / 12, tn = wgid - tm * 12;
  int m0 = tm * 256, n0 = tn * 256;

  // staging map: linear LDS dest chunk o -> (row, k) source, inverse of the
  // read-side swizzle (both sides same involution, rule #21).
  int ro[2], ke[2];
#pragma unroll
  for (int j = 0; j < 2; ++j) {
    int o = j * 8192 + tid * 16;
    int s = o >> 10, w10 = o & 1023;
    int lg = w10 ^ (((w10 >> 9) & 1) << 5);
    ro[j] = ((s >> 1) << 4) + (lg >> 6);
    ke[j] = ((s & 1) << 5) + ((lg & 63) >> 1);
  }
  auto stage_half = [&](int ldsoff, const unsigned short* src, int rb, int k0) {
#pragma unroll
    for (int j = 0; j < 2; ++j)
      async16(lds + ldsoff + j * 8192 + w * 1024,
              src + (size_t)(rb + ro[j]) * 1024 + (k0 + ke[j]));
  };
  auto stA = [&](int t) {
    int d = (t & 1) << 16;
    stage_half(d, A, m0, t * 64);
    stage_half(d + 16384, A, m0 + 128, t * 64);
  };
  auto stB0 = [&](int t) { stage_half(((t & 1) << 16) + 32768, Bm, n0, t * 64); };
  auto stB1 = [&](int t) { stage_half(((t & 1) << 16) + 49152, Bm, n0 + 128, t * 64); };

  // read-side per-lane swizzled offset within a 1KB subtile:
  // logical (l&15)*64 + (l>>4)*16, XOR bit5 with row-bit3 -> 8 lanes per 4-bank
  // group (throughput-optimal ds_read_b128).
  const int lswz = (((lane & 15) << 6) | ((lane >> 4) << 4)) ^ ((lane & 8) << 2);

  f32x4 acc[8][4];
#pragma unroll
  for (int i = 0; i < 8; ++i)
#pragma unroll
    for (int j = 0; j < 4; ++j)
#pragma unroll
      for (int e = 0; e < 4; ++e) acc[i][j][e] = 0.f;

  // prologue: t0 fully, t1.B0/B1; leave t1.B in flight.
  stA(0); stB0(0); stB1(0); stB0(1); stB1(1);
  asm volatile("s_waitcnt vmcnt(4)");
  __builtin_amdgcn_s_barrier();
  __builtin_amdgcn_sched_barrier(0);

#pragma unroll 1
  for (int it = 0; it < 8; ++it) {
    const int u = it * 2;
    const bool pf = it < 7;
#pragma unroll
    for (int G = 0; G < 2; ++G) {
      const char* abase = lds + (G << 16) + wm * 16384 + lswz;
      const char* bbase = lds + (G << 16) + 32768 + (wn >> 1) * 16384 + ((wn & 1) << 13) + lswz;
      bf16x8 bF[4][2];
#pragma unroll
      for (int ph = 0; ph < 4; ++ph) {
        if (ph == 0) {
#pragma unroll
          for (int n = 0; n < 4; ++n)
#pragma unroll
            for (int ks = 0; ks < 2; ++ks)
              bF[n][ks] = dsr128(bbase + (n * 2 + ks) * 1024);
        }
        bf16x8 aF[2][2];
#pragma unroll
        for (int mm = 0; mm < 2; ++mm)
#pragma unroll
          for (int ks = 0; ks < 2; ++ks)
            aF[mm][ks] = dsr128(abase + ((ph * 2 + mm) * 2 + ks) * 1024);
        // prefetch issue (wave-uniform guards; regions freed by prior barriers)
        if (G == 0) {
          if (ph == 0) stA(u + 1);
          else if (ph == 1) { if (pf) stB0(u + 2); }
          else if (ph == 2) { if (pf) stB1(u + 2); }
        } else {
          if (ph == 0) { if (pf) stA(u + 2); }
          else if (ph == 1) { if (pf) stB0(u + 3); }
          else if (ph == 2) { if (pf) stB1(u + 3); }
        }
        __builtin_amdgcn_s_barrier();
        asm volatile("s_waitcnt lgkmcnt(0)");
        __builtin_amdgcn_sched_barrier(0);
        __builtin_amdgcn_s_setprio(1);
#pragma unroll
        for (int ks = 0; ks < 2; ++ks)
#pragma unroll
          for (int mm = 0; mm < 2; ++mm)
#pragma unroll
            for (int n = 0; n < 4; ++n)
              acc[ph * 2 + mm][n] = __builtin_amdgcn_mfma_f32_16x16x32_bf16(
                  aF[mm][ks], bF[n][ks], acc[ph * 2 + mm][n], 0, 0, 0);
        __builtin_amdgcn_s_setprio(0);
        if (ph == 3) {
          if (G == 0) {
            if (pf) asm volatile("s_waitcnt vmcnt(4)");
            else    asm volatile("s_waitcnt vmcnt(0)");
          } else {
            if (pf) asm volatile("s_waitcnt vmcnt(4)");
          }
        }
        __builtin_amdgcn_s_barrier();
        __builtin_amdgcn_sched_barrier(0);
      }
    }
  }

  // epilogue. C fragment: col(n) = lane&15, row(s) = (lane>>4)*4 + e.
  const int which = tn >> 2;
  const int ng = n0 & 1023;
  const int b = m0 >> 10;
  const int r = lane & 15, qq = lane >> 4;
  const int sb = (m0 & 1023) + wm * 128 + qq * 4;

  if (which != 2) {
    // q / k: scattered 2B stores into [b][h][s][d] (proven path).
    const float* bp = which == 0 ? bq : bk;
    unsigned short* base = qkv + ((size_t)which << 23) + ((size_t)b << 20);
#pragma unroll
    for (int n = 0; n < 4; ++n) {
      int n_in = ng + wn * 64 + n * 16 + r;
      float bias = bp[n_in];
      unsigned short* dp = base + ((size_t)(n_in >> 6) << 16) + (n_in & 63);
#pragma unroll
      for (int m = 0; m < 8; ++m)
#pragma unroll
        for (int e = 0; e < 4; ++e)
          dp[(size_t)(sb + m * 16 + e) << 6] = (unsigned short)rne16(acc[m][n][e] + bias);
    }
  } else {
    // v: store V^T [b][h][d][s] directly — each lane owns 4 consecutive s
    // (e=0..3) at fixed d, packed as one 8B store; 4-lane groups give 32B runs.
    unsigned short* vbase = vt + ((size_t)b << 20);
#pragma unroll
    for (int n = 0; n < 4; ++n) {
      int n_in = ng + wn * 64 + n * 16 + r;
      float bias = bv[n_in];
      unsigned short* dp = vbase + ((size_t)n_in << 10) + sb;
#pragma unroll
      for (int m = 0; m < 8; ++m) {
        uint2 pk;
        pk.x = packbf(acc[m][n][0] + bias, acc[m][n][1] + bias);
        pk.y = packbf(acc[m][n][2] + bias, acc[m][n][3] + bias);
        *(uint2*)(dp + m * 16) = pk;
      }
    }
  }
}

// ---------------- attention: S^T = K*Q^T, softmax (no max-sub), O^T = V^T*P ----------------
// 1024 blocks; block = (b,h, 128-qrow chunk); wave = 32 qrows. 128-key tiles,
// single-buffered K/V staging. XCD swizzle: b = blockIdx&7 so all chunks of
// one (b,h) share an XCD's L2 copy of K/V.
__global__ __launch_bounds__(256, 4) void k_attn(const unsigned short* __restrict__ qg,
                                                 const unsigned short* __restrict__ kg,
                                                 const unsigned short* __restrict__ vtg,
                                                 const float* __restrict__ maskg,
                                                 float* __restrict__ out) {
  __shared__ __align__(16) char lds[36864];
  char* KF = lds;                     // 16 KB: K fragments (128 keys x 64 dims)
  char* VF = lds + 16384;             // 16 KB: V^T fragments (64 dims x 128 keys)
  float* MK = (float*)(lds + 32768);  // 4 KB: mask row * log2(e)
  int tid = threadIdx.x, w = tid >> 6, lane = tid & 63, l5 = lane & 31, q5 = lane >> 5;
  int idx = blockIdx.x;
  int bi = idx & 7;                   // batch == XCD (round-robin dispatch heuristic)
  int j = idx >> 3;
  int h = j >> 3, qc = j & 7;
  int bh = bi * 16 + h, s0 = qc * 128;
  const unsigned short* qb = qg + ((size_t)bh << 16);
  const unsigned short* kb = kg + ((size_t)bh << 16);
  const unsigned short* vb = vtg + ((size_t)bh << 16);
  const float LG = 1.4426950408889634f;
  const float C1 = 0.125f * LG;

  {
    float4 mv = *(const float4*)(maskg + (size_t)bi * 1024 + tid * 4);
    mv.x *= LG; mv.y *= LG; mv.z *= LG; mv.w *= LG;
    *(float4*)(MK + tid * 4) = mv;
  }

  bf16x8 qfr[4];
#pragma unroll
  for (int ds = 0; ds < 4; ++ds)
    qfr[ds] = *(const bf16x8*)(qb + (size_t)(s0 + w * 32 + l5) * 64 + ds * 16 + q5 * 8);

  f32x16 O[2];
#pragma unroll
  for (int i = 0; i < 2; ++i)
#pragma unroll
    for (int e = 0; e < 16; ++e) O[i][e] = 0.f;
  float lsum = 0.f;

#pragma unroll 1
  for (int kt = 0; kt < 8; ++kt) {
    int k0 = kt * 128;
    __syncthreads();
#pragma unroll
    for (int t = 0; t < 4; ++t) {
      int f = w * 4 + t, mt = f >> 2, ds = f & 3;
      async16(KF + f * 1024, kb + (size_t)(k0 + mt * 32 + l5) * 64 + ds * 16 + q5 * 8);
    }
#pragma unroll
    for (int t = 0; t < 4; ++t) {
      int f = w * 4 + t, dt = f >> 3, ks = f & 7;
      async16(VF + f * 1024, vb + (size_t)(dt * 32 + l5) * 1024 + k0 + ks * 16 + q5 * 8);
    }
    __syncthreads();

#pragma unroll
    for (int mt = 0; mt < 4; ++mt) {
      f32x16 S;
#pragma unroll
      for (int e = 0; e < 16; ++e) S[e] = 0.f;
#pragma unroll
      for (int ds = 0; ds < 4; ++ds) {
        bf16x8 a = *(const bf16x8*)(KF + (mt * 4 + ds) * 1024 + lane * 16);
        S = __builtin_amdgcn_mfma_f32_32x32x16_bf16(a, qfr[ds], S, 0, 0, 0);
      }
      float p[16];
#pragma unroll
      for (int g4 = 0; g4 < 4; ++g4) {
        float4 mv = *(const float4*)(MK + k0 + mt * 32 + g4 * 8 + q5 * 4);
        p[g4 * 4 + 0] = __builtin_amdgcn_exp2f(S[g4 * 4 + 0] * C1 + mv.x);
        p[g4 * 4 + 1] = __builtin_amdgcn_exp2f(S[g4 * 4 + 1] * C1 + mv.y);
        p[g4 * 4 + 2] = __builtin_amdgcn_exp2f(S[g4 * 4 + 2] * C1 + mv.z);
        p[g4 * 4 + 3] = __builtin_amdgcn_exp2f(S[g4 * 4 + 3] * C1 + mv.w);
      }
      unsigned p2[8];
#pragma unroll
      for (int e = 0; e < 16; ++e) lsum += p[e];
#pragma unroll
      for (int jj = 0; jj < 8; ++jj) p2[jj] = packbf_fast(p[2 * jj], p[2 * jj + 1]);
#pragma unroll
      for (int kh = 0; kh < 2; ++kh) {
        int ks = mt * 2 + kh, gp = kh * 4;
        bf16x8 av0 = *(const bf16x8*)(VF + (0 * 8 + ks) * 1024 + lane * 16);
        bf16x8 av1 = *(const bf16x8*)(VF + (1 * 8 + ks) * 1024 + lane * 16);
        unsigned o0 = p2[gp + 0], o1 = p2[gp + 1];
        unsigned o2 = p2[gp + 2], o3 = p2[gp + 3];
        unsigned t0 = __shfl_xor((int)o0, 32);
        unsigned t1 = __shfl_xor((int)o1, 32);
        unsigned t2 = __shfl_xor((int)o2, 32);
        unsigned t3 = __shfl_xor((int)o3, 32);
        uint4 fu;
        fu.x = q5 ? t2 : o0;
        fu.y = q5 ? t3 : o1;
        fu.z = q5 ? o2 : t0;
        fu.w = q5 ? o3 : t1;
        bf16x8 bfrag = __builtin_bit_cast(bf16x8, fu);
        O[0] = __builtin_amdgcn_mfma_f32_32x32x16_bf16(av0, bfrag, O[0], 0, 0, 0);
        O[1] = __builtin_amdgcn_mfma_f32_32x32x16_bf16(av1, bfrag, O[1], 0, 0, 0);
      }
    }
  }

  // epilogue: normalize, transpose O^T via wave-private swizzled LDS, store coalesced.
  __syncthreads();
  float* Ob = (float*)(lds + w * 8192);
  float lt = lsum + __shfl_xor(lsum, 32);
  float rinv = 1.0f / lt;
#pragma unroll
  for (int dt = 0; dt < 2; ++dt)
#pragma unroll
    for (int g4 = 0; g4 < 4; ++g4) {
      float4 val;
      val.x = O[dt][g4 * 4 + 0] * rinv;
      val.y = O[dt][g4 * 4 + 1] * rinv;
      val.z = O[dt][g4 * 4 + 2] * rinv;
      val.w = O[dt][g4 * 4 + 3] * rinv;
      int c = dt * 8 + g4 * 2 + q5;
      *(float4*)(Ob + l5 * 64 + (c ^ (l5 & 15)) * 4) = val;
    }
#pragma unroll
  for (int t = 0; t < 8; ++t) {
    int qr = t * 4 + (lane >> 4), cr = lane & 15;
    float4 vv = *(const float4*)(Ob + qr * 64 + (cr ^ (qr & 15)) * 4);
    int s = s0 + w * 32 + qr;
    *(float4*)(out + (((size_t)(bi * 1024 + s)) << 10) + (h << 6) + (cr << 2)) = vv;
  }
}

extern "C" void kernel_launch(void* const* d_in, const int* in_sizes, int n_in,
                              void* d_out, int out_size, void* d_ws, size_t ws_size,
                              hipStream_t stream) {
  (void)in_sizes; (void)n_in; (void)out_size; (void)ws_size;
  const float* hidden = (const float*)d_in[0];
  const float* mask = (const float*)d_in[1];
  const float* Wq = (const float*)d_in[2];
  const float* bq = (const float*)d_in[3];
  const float* Wk = (const float*)d_in[4];
  const float* bk = (const float*)d_in[5];
  const float* Wv = (const float*)d_in[6];
  const float* bv = (const float*)d_in[7];
  float* out = (float*)d_out;
  char* ws = (char*)d_ws;
  unsigned short* hbf = (unsigned short*)ws;                  // 16,777,216 B
  unsigned short* wt  = (unsigned short*)(ws + 16777216);     //  6,291,456 B
  unsigned short* qkv = (unsigned short*)(ws + 23068672);     // 33,554,432 B (q,k)
  unsigned short* vt  = (unsigned short*)(ws + 56623104);     // 16,777,216 B (v^T)

  k_prep<<<11264, 256, 0, stream>>>(hidden, hbf, Wq, Wk, Wv, wt);
  k_gemm<<<384, 512, 0, stream>>>(hbf, wt, bq, bk, bv, qkv, vt);
  k_attn<<<1024, 256, 0, stream>>>(qkv, qkv + 8388608, vt, mask, out);
}

// Round 2
// 218.712 us; speedup vs baseline: 1.1616x; 1.0101x over previous
//
#include <hip/hip_runtime.h>

// BertSelfAttention on MI355X: bf16 MFMA QKV GEMM + flash-style attention.
// B=8 S=1024 HID=1024 NH=16 HD=64.
// R8: fix k_gemm grid quantization. R7's 256x256 tile gave 384 blocks at
// 1 block/CU (128KB LDS) = 1.5 sequential rounds on 256 CUs -> ~33% idle-CU
// time (measured MfmaUtil 26% was round-2-deflated). Re-tile to 256x128:
// grid = 32x24 = 768 blocks = exactly 3 full rounds. LDS 96KB (2 x (A 32KB +
// B 16KB)). Schedule: 2 phases per K-tile (16 MFMA each), counted vmcnt(2)
// at G-boundaries only, same barrier-separated region reuse as R7, setprio(1)
// around MFMA, sched_barrier(0) fences. Wave grid 4m x 2n (wave tile 64x64,
// acc 4x4 f32x4). Epilogue re-derived for BN=128 (q/k/v boundaries stay
// tile-aligned: which = tn>>3). k_prep / k_attn unchanged.

typedef __bf16 bf16x8 __attribute__((ext_vector_type(8)));
typedef float f32x4 __attribute__((ext_vector_type(4)));
typedef float f32x16 __attribute__((ext_vector_type(16)));
typedef int i32x4 __attribute__((ext_vector_type(4)));

__device__ __forceinline__ unsigned rne16(float x) {
  unsigned u = __builtin_bit_cast(unsigned, x);
  return (u + 0x7fffu + ((u >> 16) & 1u)) >> 16;
}
__device__ __forceinline__ unsigned packbf(float lo, float hi) {
  return rne16(lo) | (rne16(hi) << 16);
}
// fast pack (round-half-up) for softmax probabilities.
__device__ __forceinline__ unsigned packbf_fast(float lo, float hi) {
  unsigned ul = __builtin_bit_cast(unsigned, lo) + 0x8000u;
  unsigned uh = __builtin_bit_cast(unsigned, hi) + 0x8000u;
  return __builtin_amdgcn_perm(uh, ul, 0x07060302u);
}
// async global->LDS, 16B per lane; LDS dst is wave-uniform base + lane*16.
__device__ __forceinline__ void async16(void* l, const void* g) {
  __builtin_amdgcn_global_load_lds((const __attribute__((address_space(1))) void*)g,
                                   (__attribute__((address_space(3))) void*)l, 16, 0, 0);
}
// inline-asm ds_read_b128 (ordering enforced by barriers + explicit waitcnt +
// sched_barrier(0) per rule #18).
__device__ __forceinline__ bf16x8 dsr128(const char* p) {
  i32x4 r;
  unsigned a = (unsigned)(size_t)(const __attribute__((address_space(3))) char*)p;
  asm volatile("ds_read_b128 %0, %1" : "=v"(r) : "v"(a));
  return __builtin_bit_cast(bf16x8, r);
}

// ---------------- fused: hidden fp32->bf16 (blocks 0..8191) + W transpose (8192..11263) ----
__global__ __launch_bounds__(256) void k_prep(const float* __restrict__ h,
                                              unsigned short* __restrict__ hbf,
                                              const float* __restrict__ Wq,
                                              const float* __restrict__ Wk,
                                              const float* __restrict__ Wv,
                                              unsigned short* __restrict__ wt) {
  __shared__ float t[32][33];
  int bid = blockIdx.x, tid = threadIdx.x;
  if (bid < 8192) {
    size_t i = (size_t)bid * 256 + tid;
    float4 v = ((const float4*)h)[i];
    uint2 r;
    r.x = packbf(v.x, v.y);
    r.y = packbf(v.z, v.w);
    ((uint2*)hbf)[i] = r;
  } else {
    int id = bid - 8192;           // 0..3071
    int which = id >> 10;
    int sub = id & 1023;
    int c0 = (sub & 31) * 32, k0 = (sub >> 5) * 32;
    const float* W = which == 0 ? Wq : (which == 1 ? Wk : Wv);
    int tx = tid & 31, ty = tid >> 5;
#pragma unroll
    for (int i = 0; i < 4; ++i) {
      int r = ty + i * 8;
      t[r][tx] = W[(size_t)(k0 + r) * 1024 + c0 + tx];
    }
    __syncthreads();
#pragma unroll
    for (int i = 0; i < 4; ++i) {
      int r = ty + i * 8;
      wt[((size_t)which * 1024 + c0 + r) * 1024 + k0 + tx] = (unsigned short)rne16(t[tx][r]);
    }
  }
}

// ---------------- QKV GEMM: [8192x1024] x [1024x3072]^T + bias, 256x128 tile ----------------
// LDS per buffer d (48KB each at d*49152): A [256][64] as two 16KB halves
// (+0: rows 0-127, +16384: rows 128-255), B [128][64] at +32768. Within each
// 1KB subtile (16 rows x 32 cols bf16) byte offsets are XOR-swizzled
// (off ^= ((off>>9)&1)<<5); staging uses the inverse-swizzled global source
// (rule #21), reads use the swizzled lane offset -> conflict-free ds_read_b128.
// Per iteration (K-tiles u=2i in db0, v=2i+1 in db1), 2 phases per K-tile:
//  G0.ph0: read u.B(8)+u.A01(4); stage v.A -> db1.A   [db1.A freed prev iter]
//  G0.ph1: read u.A23(4);        stage (u+2).B -> db0.B [freed by ph0 barrier]
//          end: vmcnt(2)  [v.A,v.B landed; (u+2).B in flight]
//  G1.ph0: read v.B+v.A01;       stage (u+2).A -> db0.A [freed by G0 barriers]
//  G1.ph1: read v.A23;           stage (u+3).B -> db1.B [freed by ph0 barrier]
//          end: vmcnt(2)  [(u+2).A,B landed; (u+3).B in flight]
__global__ __launch_bounds__(512, 2) void k_gemm(const unsigned short* __restrict__ A,
                                                 const unsigned short* __restrict__ Bm,
                                                 const float* __restrict__ bq,
                                                 const float* __restrict__ bk,
                                                 const float* __restrict__ bv,
                                                 unsigned short* __restrict__ qkv,
                                                 unsigned short* __restrict__ vt) {
  __shared__ __align__(16) char lds[98304];
  const int tid = threadIdx.x;
  const int w = tid >> 6, lane = tid & 63;
  const int wm = w >> 1, wn = w & 1;  // wave tile 64 rows x 64 cols

  // bijective XCD swizzle: 768 blocks = 8 XCDs x 96; tn fastest within a chunk
  // so each XCD's L2 holds 4 A-panels (2MB) while B columns rotate.
  int orig = blockIdx.x;
  int wgid = (orig & 7) * 96 + (orig >> 3);
  int tm = wgid / 24, tn = wgid - tm * 24;
  int m0 = tm * 256, n0 = tn * 128;

  // staging map: linear LDS dest chunk o -> (row, k) source, inverse of the
  // read-side swizzle (both sides same involution).
  int ro[2], ke[2];
#pragma unroll
  for (int j = 0; j < 2; ++j) {
    int o = j * 8192 + tid * 16;
    int s = o >> 10, w10 = o & 1023;
    int lg = w10 ^ (((w10 >> 9) & 1) << 5);
    ro[j] = ((s >> 1) << 4) + (lg >> 6);
    ke[j] = ((s & 1) << 5) + ((lg & 63) >> 1);
  }
  auto stage_half = [&](int ldsoff, const unsigned short* src, int rb, int k0) {
#pragma unroll
    for (int j = 0; j < 2; ++j)
      async16(lds + ldsoff + j * 8192 + w * 1024,
              src + (size_t)(rb + ro[j]) * 1024 + (k0 + ke[j]));
  };
  auto stA = [&](int t) {
    int d = (t & 1) * 49152;
    stage_half(d, A, m0, t * 64);
    stage_half(d + 16384, A, m0 + 128, t * 64);
  };
  auto stB = [&](int t) { stage_half((t & 1) * 49152 + 32768, Bm, n0, t * 64); };

  // read-side per-lane swizzled offset within a 1KB subtile.
  const int lswz = (((lane & 15) << 6) | ((lane >> 4) << 4)) ^ ((lane & 8) << 2);

  f32x4 acc[4][4];
#pragma unroll
  for (int i = 0; i < 4; ++i)
#pragma unroll
    for (int j = 0; j < 4; ++j)
#pragma unroll
      for (int e = 0; e < 4; ++e) acc[i][j][e] = 0.f;

  // prologue: t0 fully, t1.B; leave t1.B in flight.
  stA(0); stB(0); stB(1);
  asm volatile("s_waitcnt vmcnt(2)");
  __builtin_amdgcn_s_barrier();
  __builtin_amdgcn_sched_barrier(0);

#pragma unroll 1
  for (int it = 0; it < 8; ++it) {
    const int u = it * 2;
    const bool pf = it < 7;
#pragma unroll
    for (int G = 0; G < 2; ++G) {
      const char* abase = lds + G * 49152 + (wm >> 1) * 16384 + lswz;
      const char* bbase = lds + G * 49152 + 32768 + lswz;
      bf16x8 bF[4][2];
#pragma unroll
      for (int ph = 0; ph < 2; ++ph) {
        if (ph == 0) {
#pragma unroll
          for (int n = 0; n < 4; ++n)
#pragma unroll
            for (int ks = 0; ks < 2; ++ks)
              bF[n][ks] = dsr128(bbase + ((wn * 4 + n) * 2 + ks) * 1024);
        }
        bf16x8 aF[2][2];
#pragma unroll
        for (int mm = 0; mm < 2; ++mm)
#pragma unroll
          for (int ks = 0; ks < 2; ++ks)
            aF[mm][ks] =
                dsr128(abase + (((wm & 1) * 4 + ph * 2 + mm) * 2 + ks) * 1024);
        // prefetch issue (wave-uniform; target regions freed by prior barriers)
        if (G == 0) {
          if (ph == 0) stA(u + 1);
          else if (pf) stB(u + 2);
        } else {
          if (ph == 0) { if (pf) stA(u + 2); }
          else if (pf) stB(u + 3);
        }
        __builtin_amdgcn_s_barrier();
        asm volatile("s_waitcnt lgkmcnt(0)");
        __builtin_amdgcn_sched_barrier(0);
        __builtin_amdgcn_s_setprio(1);
#pragma unroll
        for (int ks = 0; ks < 2; ++ks)
#pragma unroll
          for (int mm = 0; mm < 2; ++mm)
#pragma unroll
            for (int n = 0; n < 4; ++n)
              acc[ph * 2 + mm][n] = __builtin_amdgcn_mfma_f32_16x16x32_bf16(
                  aF[mm][ks], bF[n][ks], acc[ph * 2 + mm][n], 0, 0, 0);
        __builtin_amdgcn_s_setprio(0);
        if (ph == 1) {
          if (G == 0) {
            if (pf) asm volatile("s_waitcnt vmcnt(2)");
            else    asm volatile("s_waitcnt vmcnt(0)");
          } else {
            if (pf) asm volatile("s_waitcnt vmcnt(2)");
          }
        }
        __builtin_amdgcn_s_barrier();
        __builtin_amdgcn_sched_barrier(0);
      }
    }
  }

  // epilogue. C fragment: col(n) = lane&15, row(s) = (lane>>4)*4 + e.
  const int which = tn >> 3;
  const int ng = n0 & 1023;
  const int b = m0 >> 10;
  const int r = lane & 15, qq = lane >> 4;
  const int sb = (m0 & 1023) + wm * 64 + qq * 4;

  if (which != 2) {
    // q / k: scattered 2B stores into [b][h][s][d] (proven path).
    const float* bp = which == 0 ? bq : bk;
    unsigned short* base = qkv + ((size_t)which << 23) + ((size_t)b << 20);
#pragma unroll
    for (int n = 0; n < 4; ++n) {
      int n_in = ng + wn * 64 + n * 16 + r;
      float bias = bp[n_in];
      unsigned short* dp = base + ((size_t)(n_in >> 6) << 16) + (n_in & 63);
#pragma unroll
      for (int m = 0; m < 4; ++m)
#pragma unroll
        for (int e = 0; e < 4; ++e)
          dp[(size_t)(sb + m * 16 + e) << 6] = (unsigned short)rne16(acc[m][n][e] + bias);
    }
  } else {
    // v: store V^T [b][h][d][s] directly — each lane owns 4 consecutive s
    // (e=0..3) at fixed d, packed as one 8B store; 4-lane groups give 32B runs.
    unsigned short* vbase = vt + ((size_t)b << 20);
#pragma unroll
    for (int n = 0; n < 4; ++n) {
      int n_in = ng + wn * 64 + n * 16 + r;
      float bias = bv[n_in];
      unsigned short* dp = vbase + ((size_t)n_in << 10) + sb;
#pragma unroll
      for (int m = 0; m < 4; ++m) {
        uint2 pk;
        pk.x = packbf(acc[m][n][0] + bias, acc[m][n][1] + bias);
        pk.y = packbf(acc[m][n][2] + bias, acc[m][n][3] + bias);
        *(uint2*)(dp + m * 16) = pk;
      }
    }
  }
}

// ---------------- attention: S^T = K*Q^T, softmax (no max-sub), O^T = V^T*P ----------------
// 1024 blocks; block = (b,h, 128-qrow chunk); wave = 32 qrows. 128-key tiles,
// single-buffered K/V staging. XCD swizzle: b = blockIdx&7 so all chunks of
// one (b,h) share an XCD's L2 copy of K/V.
__global__ __launch_bounds__(256, 4) void k_attn(const unsigned short* __restrict__ qg,
                                                 const unsigned short* __restrict__ kg,
                                                 const unsigned short* __restrict__ vtg,
                                                 const float* __restrict__ maskg,
                                                 float* __restrict__ out) {
  __shared__ __align__(16) char lds[36864];
  char* KF = lds;                     // 16 KB: K fragments (128 keys x 64 dims)
  char* VF = lds + 16384;             // 16 KB: V^T fragments (64 dims x 128 keys)
  float* MK = (float*)(lds + 32768);  // 4 KB: mask row * log2(e)
  int tid = threadIdx.x, w = tid >> 6, lane = tid & 63, l5 = lane & 31, q5 = lane >> 5;
  int idx = blockIdx.x;
  int bi = idx & 7;                   // batch == XCD (round-robin dispatch heuristic)
  int j = idx >> 3;
  int h = j >> 3, qc = j & 7;
  int bh = bi * 16 + h, s0 = qc * 128;
  const unsigned short* qb = qg + ((size_t)bh << 16);
  const unsigned short* kb = kg + ((size_t)bh << 16);
  const unsigned short* vb = vtg + ((size_t)bh << 16);
  const float LG = 1.4426950408889634f;
  const float C1 = 0.125f * LG;

  {
    float4 mv = *(const float4*)(maskg + (size_t)bi * 1024 + tid * 4);
    mv.x *= LG; mv.y *= LG; mv.z *= LG; mv.w *= LG;
    *(float4*)(MK + tid * 4) = mv;
  }

  bf16x8 qfr[4];
#pragma unroll
  for (int ds = 0; ds < 4; ++ds)
    qfr[ds] = *(const bf16x8*)(qb + (size_t)(s0 + w * 32 + l5) * 64 + ds * 16 + q5 * 8);

  f32x16 O[2];
#pragma unroll
  for (int i = 0; i < 2; ++i)
#pragma unroll
    for (int e = 0; e < 16; ++e) O[i][e] = 0.f;
  float lsum = 0.f;

#pragma unroll 1
  for (int kt = 0; kt < 8; ++kt) {
    int k0 = kt * 128;
    __syncthreads();
#pragma unroll
    for (int t = 0; t < 4; ++t) {
      int f = w * 4 + t, mt = f >> 2, ds = f & 3;
      async16(KF + f * 1024, kb + (size_t)(k0 + mt * 32 + l5) * 64 + ds * 16 + q5 * 8);
    }
#pragma unroll
    for (int t = 0; t < 4; ++t) {
      int f = w * 4 + t, dt = f >> 3, ks = f & 7;
      async16(VF + f * 1024, vb + (size_t)(dt * 32 + l5) * 1024 + k0 + ks * 16 + q5 * 8);
    }
    __syncthreads();

#pragma unroll
    for (int mt = 0; mt < 4; ++mt) {
      f32x16 S;
#pragma unroll
      for (int e = 0; e < 16; ++e) S[e] = 0.f;
#pragma unroll
      for (int ds = 0; ds < 4; ++ds) {
        bf16x8 a = *(const bf16x8*)(KF + (mt * 4 + ds) * 1024 + lane * 16);
        S = __builtin_amdgcn_mfma_f32_32x32x16_bf16(a, qfr[ds], S, 0, 0, 0);
      }
      float p[16];
#pragma unroll
      for (int g4 = 0; g4 < 4; ++g4) {
        float4 mv = *(const float4*)(MK + k0 + mt * 32 + g4 * 8 + q5 * 4);
        p[g4 * 4 + 0] = __builtin_amdgcn_exp2f(S[g4 * 4 + 0] * C1 + mv.x);
        p[g4 * 4 + 1] = __builtin_amdgcn_exp2f(S[g4 * 4 + 1] * C1 + mv.y);
        p[g4 * 4 + 2] = __builtin_amdgcn_exp2f(S[g4 * 4 + 2] * C1 + mv.z);
        p[g4 * 4 + 3] = __builtin_amdgcn_exp2f(S[g4 * 4 + 3] * C1 + mv.w);
      }
      unsigned p2[8];
#pragma unroll
      for (int e = 0; e < 16; ++e) lsum += p[e];
#pragma unroll
      for (int jj = 0; jj < 8; ++jj) p2[jj] = packbf_fast(p[2 * jj], p[2 * jj + 1]);
#pragma unroll
      for (int kh = 0; kh < 2; ++kh) {
        int ks = mt * 2 + kh, gp = kh * 4;
        bf16x8 av0 = *(const bf16x8*)(VF + (0 * 8 + ks) * 1024 + lane * 16);
        bf16x8 av1 = *(const bf16x8*)(VF + (1 * 8 + ks) * 1024 + lane * 16);
        unsigned o0 = p2[gp + 0], o1 = p2[gp + 1];
        unsigned o2 = p2[gp + 2], o3 = p2[gp + 3];
        unsigned t0 = __shfl_xor((int)o0, 32);
        unsigned t1 = __shfl_xor((int)o1, 32);
        unsigned t2 = __shfl_xor((int)o2, 32);
        unsigned t3 = __shfl_xor((int)o3, 32);
        uint4 fu;
        fu.x = q5 ? t2 : o0;
        fu.y = q5 ? t3 : o1;
        fu.z = q5 ? o2 : t0;
        fu.w = q5 ? o3 : t1;
        bf16x8 bfrag = __builtin_bit_cast(bf16x8, fu);
        O[0] = __builtin_amdgcn_mfma_f32_32x32x16_bf16(av0, bfrag, O[0], 0, 0, 0);
        O[1] = __builtin_amdgcn_mfma_f32_32x32x16_bf16(av1, bfrag, O[1], 0, 0, 0);
      }
    }
  }

  // epilogue: normalize, transpose O^T via wave-private swizzled LDS, store coalesced.
  __syncthreads();
  float* Ob = (float*)(lds + w * 8192);
  float lt = lsum + __shfl_xor(lsum, 32);
  float rinv = 1.0f / lt;
#pragma unroll
  for (int dt = 0; dt < 2; ++dt)
#pragma unroll
    for (int g4 = 0; g4 < 4; ++g4) {
      float4 val;
      val.x = O[dt][g4 * 4 + 0] * rinv;
      val.y = O[dt][g4 * 4 + 1] * rinv;
      val.z = O[dt][g4 * 4 + 2] * rinv;
      val.w = O[dt][g4 * 4 + 3] * rinv;
      int c = dt * 8 + g4 * 2 + q5;
      *(float4*)(Ob + l5 * 64 + (c ^ (l5 & 15)) * 4) = val;
    }
#pragma unroll
  for (int t = 0; t < 8; ++t) {
    int qr = t * 4 + (lane >> 4), cr = lane & 15;
    float4 vv = *(const float4*)(Ob + qr * 64 + (cr ^ (qr & 15)) * 4);
    int s = s0 + w * 32 + qr;
    *(float4*)(out + (((size_t)(bi * 1024 + s)) << 10) + (h << 6) + (cr << 2)) = vv;
  }
}

extern "C" void kernel_launch(void* const* d_in, const int* in_sizes, int n_in,
                              void* d_out, int out_size, void* d_ws, size_t ws_size,
                              hipStream_t stream) {
  (void)in_sizes; (void)n_in; (void)out_size; (void)ws_size;
  const float* hidden = (const float*)d_in[0];
  const float* mask = (const float*)d_in[1];
  const float* Wq = (const float*)d_in[2];
  const float* bq = (const float*)d_in[3];
  const float* Wk = (const float*)d_in[4];
  const float* bk = (const float*)d_in[5];
  const float* Wv = (const float*)d_in[6];
  const float* bv = (const float*)d_in[7];
  float* out = (float*)d_out;
  char* ws = (char*)d_ws;
  unsigned short* hbf = (unsigned short*)ws;                  // 16,777,216 B
  unsigned short* wt  = (unsigned short*)(ws + 16777216);     //  6,291,456 B
  unsigned short* qkv = (unsigned short*)(ws + 23068672);     // 33,554,432 B (q,k)
  unsigned short* vt  = (unsigned short*)(ws + 56623104);     // 16,777,216 B (v^T)

  k_prep<<<11264, 256, 0, stream>>>(hidden, hbf, Wq, Wk, Wv, wt);
  k_gemm<<<768, 512, 0, stream>>>(hbf, wt, bq, bk, bv, qkv, vt);
  k_attn<<<1024, 256, 0, stream>>>(qkv, qkv + 8388608, vt, mask, out);
}

// Round 3
// 215.692 us; speedup vs baseline: 1.1778x; 1.0140x over previous
//
#include <hip/hip_runtime.h>

// BertSelfAttention on MI355X: bf16 MFMA QKV GEMM + flash-style attention.
// B=8 S=1024 HID=1024 NH=16 HD=64.
// R9: k_gemm de-lockstepped. R8 paid 4 barriers + 2 lgkmcnt(0) drains per
// K-tile, fully serializing LDS reads (512 cyc) against MFMA (1242 cyc)
// -> 3350 cyc/tile measured vs ~1400 achievable. Now: triple-buffered LDS
// (3 x 48KB = 144KB) so stage(kt+2) never aliases the read buffer -> ONE
// barrier per K-tile; reads software-pipelined against MFMA with counted
// lgkmcnt(8); staging 2 tiles deep (~2600 cyc in flight >> 900 cyc HBM
// latency) so vmcnt(6) is ~free. Same swizzle / MFMA / epilogue / grid as R8
// (768 blocks = 3 exact rounds). k_prep / k_attn unchanged.

typedef __bf16 bf16x8 __attribute__((ext_vector_type(8)));
typedef float f32x4 __attribute__((ext_vector_type(4)));
typedef float f32x16 __attribute__((ext_vector_type(16)));
typedef int i32x4 __attribute__((ext_vector_type(4)));

__device__ __forceinline__ unsigned rne16(float x) {
  unsigned u = __builtin_bit_cast(unsigned, x);
  return (u + 0x7fffu + ((u >> 16) & 1u)) >> 16;
}
__device__ __forceinline__ unsigned packbf(float lo, float hi) {
  return rne16(lo) | (rne16(hi) << 16);
}
// fast pack (round-half-up) for softmax probabilities.
__device__ __forceinline__ unsigned packbf_fast(float lo, float hi) {
  unsigned ul = __builtin_bit_cast(unsigned, lo) + 0x8000u;
  unsigned uh = __builtin_bit_cast(unsigned, hi) + 0x8000u;
  return __builtin_amdgcn_perm(uh, ul, 0x07060302u);
}
// async global->LDS, 16B per lane; LDS dst is wave-uniform base + lane*16.
__device__ __forceinline__ void async16(void* l, const void* g) {
  __builtin_amdgcn_global_load_lds((const __attribute__((address_space(1))) void*)g,
                                   (__attribute__((address_space(3))) void*)l, 16, 0, 0);
}
// inline-asm ds_read_b128 (ordering enforced by barriers + explicit waitcnt +
// sched_barrier(0) per rule #18).
__device__ __forceinline__ bf16x8 dsr128(const char* p) {
  i32x4 r;
  unsigned a = (unsigned)(size_t)(const __attribute__((address_space(3))) char*)p;
  asm volatile("ds_read_b128 %0, %1" : "=v"(r) : "v"(a));
  return __builtin_bit_cast(bf16x8, r);
}

// ---------------- fused: hidden fp32->bf16 (blocks 0..8191) + W transpose (8192..11263) ----
__global__ __launch_bounds__(256) void k_prep(const float* __restrict__ h,
                                              unsigned short* __restrict__ hbf,
                                              const float* __restrict__ Wq,
                                              const float* __restrict__ Wk,
                                              const float* __restrict__ Wv,
                                              unsigned short* __restrict__ wt) {
  __shared__ float t[32][33];
  int bid = blockIdx.x, tid = threadIdx.x;
  if (bid < 8192) {
    size_t i = (size_t)bid * 256 + tid;
    float4 v = ((const float4*)h)[i];
    uint2 r;
    r.x = packbf(v.x, v.y);
    r.y = packbf(v.z, v.w);
    ((uint2*)hbf)[i] = r;
  } else {
    int id = bid - 8192;           // 0..3071
    int which = id >> 10;
    int sub = id & 1023;
    int c0 = (sub & 31) * 32, k0 = (sub >> 5) * 32;
    const float* W = which == 0 ? Wq : (which == 1 ? Wk : Wv);
    int tx = tid & 31, ty = tid >> 5;
#pragma unroll
    for (int i = 0; i < 4; ++i) {
      int r = ty + i * 8;
      t[r][tx] = W[(size_t)(k0 + r) * 1024 + c0 + tx];
    }
    __syncthreads();
#pragma unroll
    for (int i = 0; i < 4; ++i) {
      int r = ty + i * 8;
      wt[((size_t)which * 1024 + c0 + r) * 1024 + k0 + tx] = (unsigned short)rne16(t[tx][r]);
    }
  }
}

// ---------------- QKV GEMM: [8192x1024] x [1024x3072]^T + bias, 256x128 tile ----------------
// Triple-buffered LDS, 48KB per buffer at bufidx*49152: A [256][64] as two
// 16KB halves (+0: rows 0-127, +16384: rows 128-255), B [128][64] at +32768.
// Within each 1KB subtile (16 rows x 32 cols bf16) byte offsets are
// XOR-swizzled (off ^= ((off>>9)&1)<<5); staging uses the inverse-swizzled
// global source (rule #21), reads use the swizzled lane offset ->
// conflict-free ds_read_b128.
// Per K-tile kt (buffer kt%3):
//   issue ks0 reads(8) | issue stage(kt+2)->buf[(kt+2)%3] | issue ks1 reads(8)
//   lgkmcnt(8) -> MFMA ks0 (16, overlaps ks1 read drain)
//   lgkmcnt(0) -> MFMA ks1 (16)
//   vmcnt(6) [tile kt+1 landed; kt+2's 6 loads stay in flight] -> barrier
// buf[(kt+2)%3] holds tile kt-1 data, fully read before the barrier that
// opened tile kt -> staging is race-free with a single barrier per K-tile.
__global__ __launch_bounds__(512, 2) void k_gemm(const unsigned short* __restrict__ A,
                                                 const unsigned short* __restrict__ Bm,
                                                 const float* __restrict__ bq,
                                                 const float* __restrict__ bk,
                                                 const float* __restrict__ bv,
                                                 unsigned short* __restrict__ qkv,
                                                 unsigned short* __restrict__ vt) {
  __shared__ __align__(16) char lds[147456];
  const int tid = threadIdx.x;
  const int w = tid >> 6, lane = tid & 63;
  const int wm = w >> 1, wn = w & 1;  // wave tile 64 rows x 64 cols

  // bijective XCD swizzle: 768 blocks = 8 XCDs x 96; tn fastest within a chunk
  // so each XCD's L2 holds 4 A-panels (2MB) while B columns rotate.
  int orig = blockIdx.x;
  int wgid = (orig & 7) * 96 + (orig >> 3);
  int tm = wgid / 24, tn = wgid - tm * 24;
  int m0 = tm * 256, n0 = tn * 128;

  // staging map: linear LDS dest chunk o -> (row, k) source, inverse of the
  // read-side swizzle (both sides same involution).
  int ro[2], ke[2];
#pragma unroll
  for (int j = 0; j < 2; ++j) {
    int o = j * 8192 + tid * 16;
    int s = o >> 10, w10 = o & 1023;
    int lg = w10 ^ (((w10 >> 9) & 1) << 5);
    ro[j] = ((s >> 1) << 4) + (lg >> 6);
    ke[j] = ((s & 1) << 5) + ((lg & 63) >> 1);
  }
  auto stage_half = [&](int ldsoff, const unsigned short* src, int rb, int k0) {
#pragma unroll
    for (int j = 0; j < 2; ++j)
      async16(lds + ldsoff + j * 8192 + w * 1024,
              src + (size_t)(rb + ro[j]) * 1024 + (k0 + ke[j]));
  };
  auto stAB = [&](int t, int doff) {
    stage_half(doff, A, m0, t * 64);
    stage_half(doff + 16384, A, m0 + 128, t * 64);
    stage_half(doff + 32768, Bm, n0, t * 64);
  };

  // read-side per-lane swizzled offset within a 1KB subtile.
  const int lswz = (((lane & 15) << 6) | ((lane >> 4) << 4)) ^ ((lane & 8) << 2);

  f32x4 acc[4][4];
#pragma unroll
  for (int i = 0; i < 4; ++i)
#pragma unroll
    for (int j = 0; j < 4; ++j)
#pragma unroll
      for (int e = 0; e < 4; ++e) acc[i][j][e] = 0.f;

  // prologue: stage tiles 0 and 1; wait tile 0 (6 of 12 loads) then barrier.
  stAB(0, 0);
  stAB(1, 49152);
  asm volatile("s_waitcnt vmcnt(6)");
  __builtin_amdgcn_s_barrier();
  __builtin_amdgcn_sched_barrier(0);

  int cur = 0;  // kt % 3
#pragma unroll 1
  for (int kt = 0; kt < 16; ++kt) {
    const char* buf = lds + cur * 49152;
    int nxt2 = cur + 2; if (nxt2 >= 3) nxt2 -= 3;
    const char* abase = buf + (wm >> 1) * 16384 + lswz;
    const char* bbase = buf + 32768 + lswz;
    bf16x8 aF[4][2], bF[4][2];
    // ks0 reads (8)
#pragma unroll
    for (int n = 0; n < 4; ++n)
      bF[n][0] = dsr128(bbase + ((wn * 4 + n) * 2 + 0) * 1024);
#pragma unroll
    for (int mt = 0; mt < 4; ++mt)
      aF[mt][0] = dsr128(abase + (((wm & 1) * 4 + mt) * 2 + 0) * 1024);
    // deep prefetch: issue tile kt+2 staging now (lands ~2 tiles later).
    if (kt < 14) stAB(kt + 2, nxt2 * 49152);
    // ks1 reads (8) — drain under the ks0 MFMA cluster.
#pragma unroll
    for (int n = 0; n < 4; ++n)
      bF[n][1] = dsr128(bbase + ((wn * 4 + n) * 2 + 1) * 1024);
#pragma unroll
    for (int mt = 0; mt < 4; ++mt)
      aF[mt][1] = dsr128(abase + (((wm & 1) * 4 + mt) * 2 + 1) * 1024);
    asm volatile("s_waitcnt lgkmcnt(8)");
    __builtin_amdgcn_sched_barrier(0);
    __builtin_amdgcn_s_setprio(1);
#pragma unroll
    for (int mt = 0; mt < 4; ++mt)
#pragma unroll
      for (int n = 0; n < 4; ++n)
        acc[mt][n] = __builtin_amdgcn_mfma_f32_16x16x32_bf16(aF[mt][0], bF[n][0],
                                                             acc[mt][n], 0, 0, 0);
    __builtin_amdgcn_s_setprio(0);
    asm volatile("s_waitcnt lgkmcnt(0)");
    __builtin_amdgcn_sched_barrier(0);
    __builtin_amdgcn_s_setprio(1);
#pragma unroll
    for (int mt = 0; mt < 4; ++mt)
#pragma unroll
      for (int n = 0; n < 4; ++n)
        acc[mt][n] = __builtin_amdgcn_mfma_f32_16x16x32_bf16(aF[mt][1], bF[n][1],
                                                             acc[mt][n], 0, 0, 0);
    __builtin_amdgcn_s_setprio(0);
    // tile kt+1 must have landed in every wave before anyone reads it.
    if (kt < 14) asm volatile("s_waitcnt vmcnt(6)");
    else if (kt == 14) asm volatile("s_waitcnt vmcnt(0)");
    if (kt < 15) {
      __builtin_amdgcn_s_barrier();
      __builtin_amdgcn_sched_barrier(0);
    }
    cur = cur + 1; if (cur == 3) cur = 0;
  }

  // epilogue. C fragment: col(n) = lane&15, row(s) = (lane>>4)*4 + e.
  const int which = tn >> 3;
  const int ng = n0 & 1023;
  const int b = m0 >> 10;
  const int r = lane & 15, qq = lane >> 4;
  const int sb = (m0 & 1023) + wm * 64 + qq * 4;

  if (which != 2) {
    // q / k: scattered 2B stores into [b][h][s][d] (proven path).
    const float* bp = which == 0 ? bq : bk;
    unsigned short* base = qkv + ((size_t)which << 23) + ((size_t)b << 20);
#pragma unroll
    for (int n = 0; n < 4; ++n) {
      int n_in = ng + wn * 64 + n * 16 + r;
      float bias = bp[n_in];
      unsigned short* dp = base + ((size_t)(n_in >> 6) << 16) + (n_in & 63);
#pragma unroll
      for (int m = 0; m < 4; ++m)
#pragma unroll
        for (int e = 0; e < 4; ++e)
          dp[(size_t)(sb + m * 16 + e) << 6] = (unsigned short)rne16(acc[m][n][e] + bias);
    }
  } else {
    // v: store V^T [b][h][d][s] directly — each lane owns 4 consecutive s
    // (e=0..3) at fixed d, packed as one 8B store; 4-lane groups give 32B runs.
    unsigned short* vbase = vt + ((size_t)b << 20);
#pragma unroll
    for (int n = 0; n < 4; ++n) {
      int n_in = ng + wn * 64 + n * 16 + r;
      float bias = bv[n_in];
      unsigned short* dp = vbase + ((size_t)n_in << 10) + sb;
#pragma unroll
      for (int m = 0; m < 4; ++m) {
        uint2 pk;
        pk.x = packbf(acc[m][n][0] + bias, acc[m][n][1] + bias);
        pk.y = packbf(acc[m][n][2] + bias, acc[m][n][3] + bias);
        *(uint2*)(dp + m * 16) = pk;
      }
    }
  }
}

// ---------------- attention: S^T = K*Q^T, softmax (no max-sub), O^T = V^T*P ----------------
// 1024 blocks; block = (b,h, 128-qrow chunk); wave = 32 qrows. 128-key tiles,
// single-buffered K/V staging. XCD swizzle: b = blockIdx&7 so all chunks of
// one (b,h) share an XCD's L2 copy of K/V.
__global__ __launch_bounds__(256, 4) void k_attn(const unsigned short* __restrict__ qg,
                                                 const unsigned short* __restrict__ kg,
                                                 const unsigned short* __restrict__ vtg,
                                                 const float* __restrict__ maskg,
                                                 float* __restrict__ out) {
  __shared__ __align__(16) char lds[36864];
  char* KF = lds;                     // 16 KB: K fragments (128 keys x 64 dims)
  char* VF = lds + 16384;             // 16 KB: V^T fragments (64 dims x 128 keys)
  float* MK = (float*)(lds + 32768);  // 4 KB: mask row * log2(e)
  int tid = threadIdx.x, w = tid >> 6, lane = tid & 63, l5 = lane & 31, q5 = lane >> 5;
  int idx = blockIdx.x;
  int bi = idx & 7;                   // batch == XCD (round-robin dispatch heuristic)
  int j = idx >> 3;
  int h = j >> 3, qc = j & 7;
  int bh = bi * 16 + h, s0 = qc * 128;
  const unsigned short* qb = qg + ((size_t)bh << 16);
  const unsigned short* kb = kg + ((size_t)bh << 16);
  const unsigned short* vb = vtg + ((size_t)bh << 16);
  const float LG = 1.4426950408889634f;
  const float C1 = 0.125f * LG;

  {
    float4 mv = *(const float4*)(maskg + (size_t)bi * 1024 + tid * 4);
    mv.x *= LG; mv.y *= LG; mv.z *= LG; mv.w *= LG;
    *(float4*)(MK + tid * 4) = mv;
  }

  bf16x8 qfr[4];
#pragma unroll
  for (int ds = 0; ds < 4; ++ds)
    qfr[ds] = *(const bf16x8*)(qb + (size_t)(s0 + w * 32 + l5) * 64 + ds * 16 + q5 * 8);

  f32x16 O[2];
#pragma unroll
  for (int i = 0; i < 2; ++i)
#pragma unroll
    for (int e = 0; e < 16; ++e) O[i][e] = 0.f;
  float lsum = 0.f;

#pragma unroll 1
  for (int kt = 0; kt < 8; ++kt) {
    int k0 = kt * 128;
    __syncthreads();
#pragma unroll
    for (int t = 0; t < 4; ++t) {
      int f = w * 4 + t, mt = f >> 2, ds = f & 3;
      async16(KF + f * 1024, kb + (size_t)(k0 + mt * 32 + l5) * 64 + ds * 16 + q5 * 8);
    }
#pragma unroll
    for (int t = 0; t < 4; ++t) {
      int f = w * 4 + t, dt = f >> 3, ks = f & 7;
      async16(VF + f * 1024, vb + (size_t)(dt * 32 + l5) * 1024 + k0 + ks * 16 + q5 * 8);
    }
    __syncthreads();

#pragma unroll
    for (int mt = 0; mt < 4; ++mt) {
      f32x16 S;
#pragma unroll
      for (int e = 0; e < 16; ++e) S[e] = 0.f;
#pragma unroll
      for (int ds = 0; ds < 4; ++ds) {
        bf16x8 a = *(const bf16x8*)(KF + (mt * 4 + ds) * 1024 + lane * 16);
        S = __builtin_amdgcn_mfma_f32_32x32x16_bf16(a, qfr[ds], S, 0, 0, 0);
      }
      float p[16];
#pragma unroll
      for (int g4 = 0; g4 < 4; ++g4) {
        float4 mv = *(const float4*)(MK + k0 + mt * 32 + g4 * 8 + q5 * 4);
        p[g4 * 4 + 0] = __builtin_amdgcn_exp2f(S[g4 * 4 + 0] * C1 + mv.x);
        p[g4 * 4 + 1] = __builtin_amdgcn_exp2f(S[g4 * 4 + 1] * C1 + mv.y);
        p[g4 * 4 + 2] = __builtin_amdgcn_exp2f(S[g4 * 4 + 2] * C1 + mv.z);
        p[g4 * 4 + 3] = __builtin_amdgcn_exp2f(S[g4 * 4 + 3] * C1 + mv.w);
      }
      unsigned p2[8];
#pragma unroll
      for (int e = 0; e < 16; ++e) lsum += p[e];
#pragma unroll
      for (int jj = 0; jj < 8; ++jj) p2[jj] = packbf_fast(p[2 * jj], p[2 * jj + 1]);
#pragma unroll
      for (int kh = 0; kh < 2; ++kh) {
        int ks = mt * 2 + kh, gp = kh * 4;
        bf16x8 av0 = *(const bf16x8*)(VF + (0 * 8 + ks) * 1024 + lane * 16);
        bf16x8 av1 = *(const bf16x8*)(VF + (1 * 8 + ks) * 1024 + lane * 16);
        unsigned o0 = p2[gp + 0], o1 = p2[gp + 1];
        unsigned o2 = p2[gp + 2], o3 = p2[gp + 3];
        unsigned t0 = __shfl_xor((int)o0, 32);
        unsigned t1 = __shfl_xor((int)o1, 32);
        unsigned t2 = __shfl_xor((int)o2, 32);
        unsigned t3 = __shfl_xor((int)o3, 32);
        uint4 fu;
        fu.x = q5 ? t2 : o0;
        fu.y = q5 ? t3 : o1;
        fu.z = q5 ? o2 : t0;
        fu.w = q5 ? o3 : t1;
        bf16x8 bfrag = __builtin_bit_cast(bf16x8, fu);
        O[0] = __builtin_amdgcn_mfma_f32_32x32x16_bf16(av0, bfrag, O[0], 0, 0, 0);
        O[1] = __builtin_amdgcn_mfma_f32_32x32x16_bf16(av1, bfrag, O[1], 0, 0, 0);
      }
    }
  }

  // epilogue: normalize, transpose O^T via wave-private swizzled LDS, store coalesced.
  __syncthreads();
  float* Ob = (float*)(lds + w * 8192);
  float lt = lsum + __shfl_xor(lsum, 32);
  float rinv = 1.0f / lt;
#pragma unroll
  for (int dt = 0; dt < 2; ++dt)
#pragma unroll
    for (int g4 = 0; g4 < 4; ++g4) {
      float4 val;
      val.x = O[dt][g4 * 4 + 0] * rinv;
      val.y = O[dt][g4 * 4 + 1] * rinv;
      val.z = O[dt][g4 * 4 + 2] * rinv;
      val.w = O[dt][g4 * 4 + 3] * rinv;
      int c = dt * 8 + g4 * 2 + q5;
      *(float4*)(Ob + l5 * 64 + (c ^ (l5 & 15)) * 4) = val;
    }
#pragma unroll
  for (int t = 0; t < 8; ++t) {
    int qr = t * 4 + (lane >> 4), cr = lane & 15;
    float4 vv = *(const float4*)(Ob + qr * 64 + (cr ^ (qr & 15)) * 4);
    int s = s0 + w * 32 + qr;
    *(float4*)(out + (((size_t)(bi * 1024 + s)) << 10) + (h << 6) + (cr << 2)) = vv;
  }
}

extern "C" void kernel_launch(void* const* d_in, const int* in_sizes, int n_in,
                              void* d_out, int out_size, void* d_ws, size_t ws_size,
                              hipStream_t stream) {
  (void)in_sizes; (void)n_in; (void)out_size; (void)ws_size;
  const float* hidden = (const float*)d_in[0];
  const float* mask = (const float*)d_in[1];
  const float* Wq = (const float*)d_in[2];
  const float* bq = (const float*)d_in[3];
  const float* Wk = (const float*)d_in[4];
  const float* bk = (const float*)d_in[5];
  const float* Wv = (const float*)d_in[6];
  const float* bv = (const float*)d_in[7];
  float* out = (float*)d_out;
  char* ws = (char*)d_ws;
  unsigned short* hbf = (unsigned short*)ws;                  // 16,777,216 B
  unsigned short* wt  = (unsigned short*)(ws + 16777216);     //  6,291,456 B
  unsigned short* qkv = (unsigned short*)(ws + 23068672);     // 33,554,432 B (q,k)
  unsigned short* vt  = (unsigned short*)(ws + 56623104);     // 16,777,216 B (v^T)

  k_prep<<<11264, 256, 0, stream>>>(hidden, hbf, Wq, Wk, Wv, wt);
  k_gemm<<<768, 512, 0, stream>>>(hbf, wt, bq, bk, bv, qkv, vt);
  k_attn<<<1024, 256, 0, stream>>>(qkv, qkv + 8388608, vt, mask, out);
}

// Round 4
// 211.889 us; speedup vs baseline: 1.1990x; 1.0179x over previous
//
#include <hip/hip_runtime.h>

// BertSelfAttention on MI355X: bf16 MFMA QKV GEMM + flash-style attention.
// B=8 S=1024 HID=1024 NH=16 HD=64.
// R10: occupancy, not schedule. R7-R9 (three different hand schedules, all
// 1 block/CU) are pinned at ~1260-1460 FLOP/cyc/CU: every intra-block stall
// idles the whole CU. m97's 874 TF came at 3 blocks/CU via implicit
// cross-block overlap (m114), with per-tile overhead ~430 cyc vs our ~2000.
// k_gemm re-tiled to 128x128, BK=64, 64KB double-buffered LDS, 256 threads
// (4 waves, 2x2 wave grid) -> 2 blocks/CU; grid 64x24=1536 = 3 exact rounds
// of 512. Interior is the proven compiler-scheduled m97 shape: __syncthreads
// 2-barrier loop, global_load_lds staging issued before compute, plain C++
// swizzled ds_read_b128 (compiler inserts counted lgkmcnt), no inline asm.
// Swizzle maps and epilogues carried over verbatim (re-indexed for 4 waves).
// k_prep / k_attn unchanged.

typedef __bf16 bf16x8 __attribute__((ext_vector_type(8)));
typedef float f32x4 __attribute__((ext_vector_type(4)));
typedef float f32x16 __attribute__((ext_vector_type(16)));

__device__ __forceinline__ unsigned rne16(float x) {
  unsigned u = __builtin_bit_cast(unsigned, x);
  return (u + 0x7fffu + ((u >> 16) & 1u)) >> 16;
}
__device__ __forceinline__ unsigned packbf(float lo, float hi) {
  return rne16(lo) | (rne16(hi) << 16);
}
// fast pack (round-half-up) for softmax probabilities.
__device__ __forceinline__ unsigned packbf_fast(float lo, float hi) {
  unsigned ul = __builtin_bit_cast(unsigned, lo) + 0x8000u;
  unsigned uh = __builtin_bit_cast(unsigned, hi) + 0x8000u;
  return __builtin_amdgcn_perm(uh, ul, 0x07060302u);
}
// async global->LDS, 16B per lane; LDS dst is wave-uniform base + lane*16.
__device__ __forceinline__ void async16(void* l, const void* g) {
  __builtin_amdgcn_global_load_lds((const __attribute__((address_space(1))) void*)g,
                                   (__attribute__((address_space(3))) void*)l, 16, 0, 0);
}

// ---------------- fused: hidden fp32->bf16 (blocks 0..8191) + W transpose (8192..11263) ----
__global__ __launch_bounds__(256) void k_prep(const float* __restrict__ h,
                                              unsigned short* __restrict__ hbf,
                                              const float* __restrict__ Wq,
                                              const float* __restrict__ Wk,
                                              const float* __restrict__ Wv,
                                              unsigned short* __restrict__ wt) {
  __shared__ float t[32][33];
  int bid = blockIdx.x, tid = threadIdx.x;
  if (bid < 8192) {
    size_t i = (size_t)bid * 256 + tid;
    float4 v = ((const float4*)h)[i];
    uint2 r;
    r.x = packbf(v.x, v.y);
    r.y = packbf(v.z, v.w);
    ((uint2*)hbf)[i] = r;
  } else {
    int id = bid - 8192;           // 0..3071
    int which = id >> 10;
    int sub = id & 1023;
    int c0 = (sub & 31) * 32, k0 = (sub >> 5) * 32;
    const float* W = which == 0 ? Wq : (which == 1 ? Wk : Wv);
    int tx = tid & 31, ty = tid >> 5;
#pragma unroll
    for (int i = 0; i < 4; ++i) {
      int r = ty + i * 8;
      t[r][tx] = W[(size_t)(k0 + r) * 1024 + c0 + tx];
    }
    __syncthreads();
#pragma unroll
    for (int i = 0; i < 4; ++i) {
      int r = ty + i * 8;
      wt[((size_t)which * 1024 + c0 + r) * 1024 + k0 + tx] = (unsigned short)rne16(t[tx][r]);
    }
  }
}

// ---------------- QKV GEMM: [8192x1024] x [1024x3072]^T + bias, 128x128 tile ----------------
// Double-buffered LDS, 32KB per buffer: A [128][64] (16KB) at +0, B [128][64]
// (16KB) at +16384. Within each 1KB subtile (16 rows x 32 cols bf16) byte
// offsets are XOR-swizzled (off ^= ((off>>9)&1)<<5); staging uses the
// inverse-swizzled global source (rule #21), reads use the swizzled lane
// offset -> conflict-free ds_read_b128. 4 waves, wave grid 2m x 2n, wave
// tile 64x64 (acc 4x4 f32x4, 32 MFMA/wave/K-tile). 2 blocks/CU (64KB LDS):
// intra-block barrier/vmcnt drains overlap with the co-resident block's
// MFMA stream (m114 mechanism) -- no hand scheduling needed.
__global__ __launch_bounds__(256, 2) void k_gemm(const unsigned short* __restrict__ A,
                                                 const unsigned short* __restrict__ Bm,
                                                 const float* __restrict__ bq,
                                                 const float* __restrict__ bk,
                                                 const float* __restrict__ bv,
                                                 unsigned short* __restrict__ qkv,
                                                 unsigned short* __restrict__ vt) {
  __shared__ __align__(16) char lds[65536];
  const int tid = threadIdx.x;
  const int w = tid >> 6, lane = tid & 63;
  const int wm = w >> 1, wn = w & 1;  // wave tile 64 rows x 64 cols

  // bijective XCD swizzle: 1536 blocks = 8 XCDs x 192; tn fastest within a
  // chunk so each XCD's L2 holds a 1024-row A panel (2MB) while B rotates.
  int orig = blockIdx.x;
  int wgid = (orig & 7) * 192 + (orig >> 3);
  int tm = wgid / 24, tn = wgid - tm * 24;
  int m0 = tm * 128, n0 = tn * 128;

  // staging map: linear LDS dest chunk o (16KB region, 256 threads x 16B x 4)
  // -> (row, k) source, inverse of the read-side swizzle (same involution).
  int ro[4], ke[4];
#pragma unroll
  for (int j = 0; j < 4; ++j) {
    int o = j * 4096 + tid * 16;
    int s = o >> 10, w10 = o & 1023;
    int lg = w10 ^ (((w10 >> 9) & 1) << 5);
    ro[j] = ((s >> 1) << 4) + (lg >> 6);
    ke[j] = ((s & 1) << 5) + ((lg & 63) >> 1);
  }
  auto stage = [&](int kt, char* buf) {
    const unsigned short* As = A + (size_t)m0 * 1024 + kt * 64;
    const unsigned short* Bs = Bm + (size_t)n0 * 1024 + kt * 64;
#pragma unroll
    for (int j = 0; j < 4; ++j) {
      async16(buf + j * 4096 + tid * 16, As + (size_t)ro[j] * 1024 + ke[j]);
      async16(buf + 16384 + j * 4096 + tid * 16, Bs + (size_t)ro[j] * 1024 + ke[j]);
    }
  };

  // read-side per-lane swizzled offset within a 1KB subtile.
  const int lswz = (((lane & 15) << 6) | ((lane >> 4) << 4)) ^ ((lane & 8) << 2);

  f32x4 acc[4][4];
#pragma unroll
  for (int i = 0; i < 4; ++i)
#pragma unroll
    for (int j = 0; j < 4; ++j)
#pragma unroll
      for (int e = 0; e < 4; ++e) acc[i][j][e] = 0.f;

  auto compute = [&](const char* buf) {
    const char* abase = buf + lswz;
    const char* bbase = buf + 16384 + lswz;
#pragma unroll
    for (int ks = 0; ks < 2; ++ks) {
      bf16x8 bF[4];
#pragma unroll
      for (int n = 0; n < 4; ++n)
        bF[n] = *(const bf16x8*)(bbase + ((size_t)((wn * 4 + n) * 2 + ks) << 10));
#pragma unroll
      for (int mt = 0; mt < 4; ++mt) {
        bf16x8 a = *(const bf16x8*)(abase + ((size_t)((wm * 4 + mt) * 2 + ks) << 10));
#pragma unroll
        for (int n = 0; n < 4; ++n)
          acc[mt][n] =
              __builtin_amdgcn_mfma_f32_16x16x32_bf16(a, bF[n], acc[mt][n], 0, 0, 0);
      }
    }
  };

  char* buf0 = lds;
  char* buf1 = lds + 32768;
  stage(0, buf0);
#pragma unroll 1
  for (int kt = 0; kt < 16; kt += 2) {
    __syncthreads();
    stage(kt + 1, buf1);
    compute(buf0);
    __syncthreads();
    if (kt + 2 < 16) stage(kt + 2, buf0);
    compute(buf1);
  }

  // epilogue. C fragment: col(n) = lane&15, row(s) = (lane>>4)*4 + e.
  const int which = tn >> 3;
  const int ng = n0 & 1023;
  const int b = m0 >> 10;
  const int r = lane & 15, qq = lane >> 4;
  const int sb = (m0 & 1023) + wm * 64 + qq * 4;

  if (which != 2) {
    // q / k: scattered 2B stores into [b][h][s][d] (proven path).
    const float* bp = which == 0 ? bq : bk;
    unsigned short* base = qkv + ((size_t)which << 23) + ((size_t)b << 20);
#pragma unroll
    for (int n = 0; n < 4; ++n) {
      int n_in = ng + wn * 64 + n * 16 + r;
      float bias = bp[n_in];
      unsigned short* dp = base + ((size_t)(n_in >> 6) << 16) + (n_in & 63);
#pragma unroll
      for (int m = 0; m < 4; ++m)
#pragma unroll
        for (int e = 0; e < 4; ++e)
          dp[(size_t)(sb + m * 16 + e) << 6] = (unsigned short)rne16(acc[m][n][e] + bias);
    }
  } else {
    // v: store V^T [b][h][d][s] directly — each lane owns 4 consecutive s
    // (e=0..3) at fixed d, packed as one 8B store; 4-lane groups give 32B runs.
    unsigned short* vbase = vt + ((size_t)b << 20);
#pragma unroll
    for (int n = 0; n < 4; ++n) {
      int n_in = ng + wn * 64 + n * 16 + r;
      float bias = bv[n_in];
      unsigned short* dp = vbase + ((size_t)n_in << 10) + sb;
#pragma unroll
      for (int m = 0; m < 4; ++m) {
        uint2 pk;
        pk.x = packbf(acc[m][n][0] + bias, acc[m][n][1] + bias);
        pk.y = packbf(acc[m][n][2] + bias, acc[m][n][3] + bias);
        *(uint2*)(dp + m * 16) = pk;
      }
    }
  }
}

// ---------------- attention: S^T = K*Q^T, softmax (no max-sub), O^T = V^T*P ----------------
// 1024 blocks; block = (b,h, 128-qrow chunk); wave = 32 qrows. 128-key tiles,
// single-buffered K/V staging. XCD swizzle: b = blockIdx&7 so all chunks of
// one (b,h) share an XCD's L2 copy of K/V.
__global__ __launch_bounds__(256, 4) void k_attn(const unsigned short* __restrict__ qg,
                                                 const unsigned short* __restrict__ kg,
                                                 const unsigned short* __restrict__ vtg,
                                                 const float* __restrict__ maskg,
                                                 float* __restrict__ out) {
  __shared__ __align__(16) char lds[36864];
  char* KF = lds;                     // 16 KB: K fragments (128 keys x 64 dims)
  char* VF = lds + 16384;             // 16 KB: V^T fragments (64 dims x 128 keys)
  float* MK = (float*)(lds + 32768);  // 4 KB: mask row * log2(e)
  int tid = threadIdx.x, w = tid >> 6, lane = tid & 63, l5 = lane & 31, q5 = lane >> 5;
  int idx = blockIdx.x;
  int bi = idx & 7;                   // batch == XCD (round-robin dispatch heuristic)
  int j = idx >> 3;
  int h = j >> 3, qc = j & 7;
  int bh = bi * 16 + h, s0 = qc * 128;
  const unsigned short* qb = qg + ((size_t)bh << 16);
  const unsigned short* kb = kg + ((size_t)bh << 16);
  const unsigned short* vb = vtg + ((size_t)bh << 16);
  const float LG = 1.4426950408889634f;
  const float C1 = 0.125f * LG;

  {
    float4 mv = *(const float4*)(maskg + (size_t)bi * 1024 + tid * 4);
    mv.x *= LG; mv.y *= LG; mv.z *= LG; mv.w *= LG;
    *(float4*)(MK + tid * 4) = mv;
  }

  bf16x8 qfr[4];
#pragma unroll
  for (int ds = 0; ds < 4; ++ds)
    qfr[ds] = *(const bf16x8*)(qb + (size_t)(s0 + w * 32 + l5) * 64 + ds * 16 + q5 * 8);

  f32x16 O[2];
#pragma unroll
  for (int i = 0; i < 2; ++i)
#pragma unroll
    for (int e = 0; e < 16; ++e) O[i][e] = 0.f;
  float lsum = 0.f;

#pragma unroll 1
  for (int kt = 0; kt < 8; ++kt) {
    int k0 = kt * 128;
    __syncthreads();
#pragma unroll
    for (int t = 0; t < 4; ++t) {
      int f = w * 4 + t, mt = f >> 2, ds = f & 3;
      async16(KF + f * 1024, kb + (size_t)(k0 + mt * 32 + l5) * 64 + ds * 16 + q5 * 8);
    }
#pragma unroll
    for (int t = 0; t < 4; ++t) {
      int f = w * 4 + t, dt = f >> 3, ks = f & 7;
      async16(VF + f * 1024, vb + (size_t)(dt * 32 + l5) * 1024 + k0 + ks * 16 + q5 * 8);
    }
    __syncthreads();

#pragma unroll
    for (int mt = 0; mt < 4; ++mt) {
      f32x16 S;
#pragma unroll
      for (int e = 0; e < 16; ++e) S[e] = 0.f;
#pragma unroll
      for (int ds = 0; ds < 4; ++ds) {
        bf16x8 a = *(const bf16x8*)(KF + (mt * 4 + ds) * 1024 + lane * 16);
        S = __builtin_amdgcn_mfma_f32_32x32x16_bf16(a, qfr[ds], S, 0, 0, 0);
      }
      float p[16];
#pragma unroll
      for (int g4 = 0; g4 < 4; ++g4) {
        float4 mv = *(const float4*)(MK + k0 + mt * 32 + g4 * 8 + q5 * 4);
        p[g4 * 4 + 0] = __builtin_amdgcn_exp2f(S[g4 * 4 + 0] * C1 + mv.x);
        p[g4 * 4 + 1] = __builtin_amdgcn_exp2f(S[g4 * 4 + 1] * C1 + mv.y);
        p[g4 * 4 + 2] = __builtin_amdgcn_exp2f(S[g4 * 4 + 2] * C1 + mv.z);
        p[g4 * 4 + 3] = __builtin_amdgcn_exp2f(S[g4 * 4 + 3] * C1 + mv.w);
      }
      unsigned p2[8];
#pragma unroll
      for (int e = 0; e < 16; ++e) lsum += p[e];
#pragma unroll
      for (int jj = 0; jj < 8; ++jj) p2[jj] = packbf_fast(p[2 * jj], p[2 * jj + 1]);
#pragma unroll
      for (int kh = 0; kh < 2; ++kh) {
        int ks = mt * 2 + kh, gp = kh * 4;
        bf16x8 av0 = *(const bf16x8*)(VF + (0 * 8 + ks) * 1024 + lane * 16);
        bf16x8 av1 = *(const bf16x8*)(VF + (1 * 8 + ks) * 1024 + lane * 16);
        unsigned o0 = p2[gp + 0], o1 = p2[gp + 1];
        unsigned o2 = p2[gp + 2], o3 = p2[gp + 3];
        unsigned t0 = __shfl_xor((int)o0, 32);
        unsigned t1 = __shfl_xor((int)o1, 32);
        unsigned t2 = __shfl_xor((int)o2, 32);
        unsigned t3 = __shfl_xor((int)o3, 32);
        uint4 fu;
        fu.x = q5 ? t2 : o0;
        fu.y = q5 ? t3 : o1;
        fu.z = q5 ? o2 : t0;
        fu.w = q5 ? o3 : t1;
        bf16x8 bfrag = __builtin_bit_cast(bf16x8, fu);
        O[0] = __builtin_amdgcn_mfma_f32_32x32x16_bf16(av0, bfrag, O[0], 0, 0, 0);
        O[1] = __builtin_amdgcn_mfma_f32_32x32x16_bf16(av1, bfrag, O[1], 0, 0, 0);
      }
    }
  }

  // epilogue: normalize, transpose O^T via wave-private swizzled LDS, store coalesced.
  __syncthreads();
  float* Ob = (float*)(lds + w * 8192);
  float lt = lsum + __shfl_xor(lsum, 32);
  float rinv = 1.0f / lt;
#pragma unroll
  for (int dt = 0; dt < 2; ++dt)
#pragma unroll
    for (int g4 = 0; g4 < 4; ++g4) {
      float4 val;
      val.x = O[dt][g4 * 4 + 0] * rinv;
      val.y = O[dt][g4 * 4 + 1] * rinv;
      val.z = O[dt][g4 * 4 + 2] * rinv;
      val.w = O[dt][g4 * 4 + 3] * rinv;
      int c = dt * 8 + g4 * 2 + q5;
      *(float4*)(Ob + l5 * 64 + (c ^ (l5 & 15)) * 4) = val;
    }
#pragma unroll
  for (int t = 0; t < 8; ++t) {
    int qr = t * 4 + (lane >> 4), cr = lane & 15;
    float4 vv = *(const float4*)(Ob + qr * 64 + (cr ^ (qr & 15)) * 4);
    int s = s0 + w * 32 + qr;
    *(float4*)(out + (((size_t)(bi * 1024 + s)) << 10) + (h << 6) + (cr << 2)) = vv;
  }
}

extern "C" void kernel_launch(void* const* d_in, const int* in_sizes, int n_in,
                              void* d_out, int out_size, void* d_ws, size_t ws_size,
                              hipStream_t stream) {
  (void)in_sizes; (void)n_in; (void)out_size; (void)ws_size;
  const float* hidden = (const float*)d_in[0];
  const float* mask = (const float*)d_in[1];
  const float* Wq = (const float*)d_in[2];
  const float* bq = (const float*)d_in[3];
  const float* Wk = (const float*)d_in[4];
  const float* bk = (const float*)d_in[5];
  const float* Wv = (const float*)d_in[6];
  const float* bv = (const float*)d_in[7];
  float* out = (float*)d_out;
  char* ws = (char*)d_ws;
  unsigned short* hbf = (unsigned short*)ws;                  // 16,777,216 B
  unsigned short* wt  = (unsigned short*)(ws + 16777216);     //  6,291,456 B
  unsigned short* qkv = (unsigned short*)(ws + 23068672);     // 33,554,432 B (q,k)
  unsigned short* vt  = (unsigned short*)(ws + 56623104);     // 16,777,216 B (v^T)

  k_prep<<<11264, 256, 0, stream>>>(hidden, hbf, Wq, Wk, Wv, wt);
  k_gemm<<<1536, 256, 0, stream>>>(hbf, wt, bq, bk, bv, qkv, vt);
  k_attn<<<1024, 256, 0, stream>>>(qkv, qkv + 8388608, vt, mask, out);
}